// Round 8
// baseline (164.746 us; speedup 1.0000x reference)
//
#include <hip/hip_runtime.h>
#include <hip/hip_bf16.h>
#include <math.h>

// spatialAttention: B=512, P=128, D=64, domain 12x12, W [64,128], out [512,128,64] f32
#define NB 512
#define NP 128
#define ND 64
#define EPSF 1e-5f
// bf16-element row stride for MFMA-read LDS arrays: 136 elems = 272 B.
// 272 % 16 == 0 -> every short8 frag access is 16B-aligned; frag-read bank
// aliasing is 2-way (free per m136).
#define SW 136

typedef __attribute__((ext_vector_type(8))) short short8;   // 8 bf16 = 4 VGPRs
typedef __attribute__((ext_vector_type(4))) float f32x4;    // MFMA accumulator

__device__ __forceinline__ short f2bf(float x) {
    __hip_bfloat16 h = __float2bfloat16(x);
    return *reinterpret_cast<short*>(&h);
}

// bin = floor(x/30) clamped to [0,11]. f64 multiply by RN64(1/30) then RN to
// f32 agrees with numpy's RN32(x/30) except w.p. ~2^-29/elem. x >= 0 here.
__device__ __forceinline__ int bin30(float x) {
    float t = (float)((double)x * (1.0 / 30.0));
    int i = (int)t;
    return i < 0 ? 0 : (i > 11 ? 11 : i);
}

__device__ __forceinline__ float fast_tanh(float x) {
    float e = __expf(2.0f * x);                    // ~1 ulp native exp
    return 1.0f - 2.0f * __builtin_amdgcn_rcpf(e + 1.0f);
}

// W as bf16 [64][128], produced by prep kernel each launch (graph-safe).
__device__ __align__(16) short g_wbf[ND * 2 * ND];

__global__ __launch_bounds__(256) void prep_w(const float* __restrict__ W) {
    int idx = blockIdx.x * 256 + threadIdx.x;     // 2048 float4
    float4 v = ((const float4*)W)[idx];
    short4 s4;
    s4.x = f2bf(v.x); s4.y = f2bf(v.y); s4.z = f2bf(v.z); s4.w = f2bf(v.w);
    *(short4*)&g_wbf[idx * 4] = s4;
}

// ============================================================================
// k1: pure elementwise stream. E = masked exp(domain[bin,bin]-dist)+eps,
// UNNORMALIZED (row softmax denominators are recovered in k2 via ones-MFMA).
// 4096 blocks x 256 thr, 8 elems/thread, 6 back-to-back float4 loads,
// ~52 VGPR -> 8 waves/SIMD. m13-shaped: max outstanding-load duty cycle.
// ============================================================================
__global__ __launch_bounds__(256, 8) void exp_kernel(
    const float* __restrict__ dist,     // [B,P,P]
    const float* __restrict__ bear,     // [B,P,P]
    const float* __restrict__ head,     // [B,P,P]
    const float* __restrict__ smask,    // [B,P]
    const float* __restrict__ domain,   // [12,12]
    short* __restrict__ wout)           // [B,P,P] bf16 unnormalized E
{
    __shared__ float s_dom[144];
    __shared__ float s_maskq[NP];
    __shared__ float s_maskp[16];

    const int blk = blockIdx.x;         // 8 blocks per batch, 16 rows per block
    const int b   = blk >> 3;
    const int p0  = (blk & 7) * 16;
    const int tid = threadIdx.x;

    if (tid < 144) s_dom[tid] = domain[tid];
    if (tid < NP)  s_maskq[tid] = smask[b * NP + tid];
    if (tid < 16)  s_maskp[tid] = smask[b * NP + p0 + tid];
    __syncthreads();

    const int p_loc = tid >> 4;                  // 0..15: row within block
    const int q0    = (tid & 15) * 8;            // column base
    const int p     = p0 + p_loc;                // row within batch
    const size_t base = ((size_t)b * NP + p) * NP + q0;

    // 6 independent fat loads, issued back-to-back (no dependent compute
    // between them -> all 6 KB in flight per wave-iteration).
    float4 d0 = *(const float4*)&dist[base], d1 = *(const float4*)&dist[base + 4];
    float4 b0 = *(const float4*)&bear[base], b1 = *(const float4*)&bear[base + 4];
    float4 h0 = *(const float4*)&head[base], h1 = *(const float4*)&head[base + 4];
    const float mp = s_maskp[p_loc];
    float4 m0 = *(const float4*)&s_maskq[q0], m1 = *(const float4*)&s_maskq[q0 + 4];

    float dv[8] = {d0.x, d0.y, d0.z, d0.w, d1.x, d1.y, d1.z, d1.w};
    float bv[8] = {b0.x, b0.y, b0.z, b0.w, b1.x, b1.y, b1.z, b1.w};
    float hv[8] = {h0.x, h0.y, h0.z, h0.w, h1.x, h1.y, h1.z, h1.w};
    float mv[8] = {m0.x, m0.y, m0.z, m0.w, m1.x, m1.y, m1.z, m1.w};

    short8 res;
    #pragma unroll
    for (int c = 0; c < 8; ++c) {
        int i1 = bin30(hv[c]), i2 = bin30(bv[c]);
        float wv = s_dom[i1 * 12 + i2] - dv[c];
        bool on = (wv > 0.0f) && (mp != 0.0f) && (mv[c] != 0.0f) && (q0 + c != p);
        res[c] = f2bf(on ? (__expf(wv) + EPSF) : EPSF);
    }
    *(short8*)&wout[base] = res;                 // 16B store
}

// ============================================================================
// k2: wh = (E/s)@h via ones-MFMA row sums; out = tanh([wh|h]@W^T + b).
// 2 blocks/batch, 256 thr = 4 waves, 16 rows/wave. LDS 36 KB -> 4 blocks/CU.
// No exp, no masks: staging (coalesced, no transpose for E) + MFMA + tanh.
// ============================================================================
__global__ __launch_bounds__(256, 4) void fuse_kernel(
    const short* __restrict__ wbuf,     // [B,P,P] bf16 unnormalized E
    const float* __restrict__ hidden,   // [B,P,D]
    const float* __restrict__ bias,     // [D]
    float* __restrict__ out)            // [B,P,D]
{
    __shared__ __align__(16) short s_w[64 * SW];   // E rows, then fused [wh|h]
    __shared__ __align__(16) short s_hT[ND * SW];  // s_hT[d][q] = h[q][d]

    const int blk  = blockIdx.x;
    const int b    = blk >> 1;
    const int half = blk & 1;
    const int tid  = threadIdx.x;
    const int lane = tid & 63;
    const int wave = tid >> 6;          // 0..3
    const int quad = lane >> 4;
    const int l16  = lane & 15;

    // ---- stage E rows (bf16, 16B chunks, coalesced, no conversion) ----
    {
        const short8* esrc = (const short8*)(wbuf + ((size_t)b * NP + half * 64) * NP);
        #pragma unroll
        for (int i = 0; i < 4; ++i) {
            int idx = tid + i * 256;          // 1024 chunks of 8 bf16
            int row = idx >> 4;               // 16 chunks per 128-col row
            int col = (idx & 15) * 8;
            *(short8*)&s_w[row * SW + col] = esrc[idx];
        }
    }
    // ---- stage hidden^T as bf16 (swizzled: transpose writes 4-way) ----
    {
        const float4* hsrc = (const float4*)(hidden + (size_t)b * NP * ND);
        #pragma unroll
        for (int i = 0; i < 8; ++i) {
            int idx = i * 256 + ((tid & 15) * 16 + (tid >> 4));
            float4 v = hsrc[idx];
            int q = idx >> 4;
            int d = (idx & 15) * 4;
            s_hT[(d + 0) * SW + q] = f2bf(v.x);
            s_hT[(d + 1) * SW + q] = f2bf(v.y);
            s_hT[(d + 2) * SW + q] = f2bf(v.z);
            s_hT[(d + 3) * SW + q] = f2bf(v.w);
        }
    }
    __syncthreads();   // the only block-wide barrier

    const int R0L = wave * 16;            // local row base (of 64)
    const int P0  = half * 64 + R0L;      // row base within batch (of 128)

    // ---- phase 2: wh_unnorm = E @ h + ones-MFMA row sums (K=128) ----
    f32x4 acc[4], accs;
    #pragma unroll
    for (int tj = 0; tj < 4; ++tj) acc[tj] = (f32x4){0.f, 0.f, 0.f, 0.f};
    accs = (f32x4){0.f, 0.f, 0.f, 0.f};

    short8 ones;
    #pragma unroll
    for (int i = 0; i < 8; ++i) ones[i] = (short)0x3F80;  // bf16 1.0

    #pragma unroll
    for (int kb = 0; kb < 4; ++kb) {
        const int ko = kb * 32 + quad * 8;
        short8 a = *(const short8*)&s_w[(R0L + l16) * SW + ko];
        accs = __builtin_amdgcn_mfma_f32_16x16x32_bf16(a, ones, accs, 0, 0, 0);
        #pragma unroll
        for (int tj = 0; tj < 4; ++tj) {
            short8 bf = *(const short8*)&s_hT[(tj * 16 + l16) * SW + ko];
            acc[tj] = __builtin_amdgcn_mfma_f32_16x16x32_bf16(a, bf, acc[tj], 0, 0, 0);
        }
    }

    // C/D row = quad*4 + r; accs rows match lane-for-lane.
    float inv[4];
    #pragma unroll
    for (int r = 0; r < 4; ++r) inv[r] = 1.0f / (accs[r] + EPSF);

    // ---- build fused rows [wh | h] in s_w (wave-local; DS is in-order) ----
    #pragma unroll
    for (int tj = 0; tj < 4; ++tj)
        #pragma unroll
        for (int r = 0; r < 4; ++r) {
            int row = R0L + quad * 4 + r;
            s_w[row * SW + tj * 16 + l16] = f2bf(acc[tj][r] * inv[r]);
        }
    // h columns straight from s_hT (bf16 passthrough; no global traffic).
    #pragma unroll 4
    for (int i = 0; i < 16; ++i)
        s_w[(R0L + i) * SW + 64 + lane] = s_hT[lane * SW + (P0 + i)];

    // ---- phase 3: out = tanh(fused @ W^T + b), B-frags from g_wbf (L2) ----
    f32x4 acc2[4];
    #pragma unroll
    for (int tj = 0; tj < 4; ++tj) acc2[tj] = (f32x4){0.f, 0.f, 0.f, 0.f};

    #pragma unroll
    for (int kb = 0; kb < 4; ++kb) {
        const int ko = kb * 32 + quad * 8;
        short8 a = *(const short8*)&s_w[(R0L + l16) * SW + ko];
        #pragma unroll
        for (int tj = 0; tj < 4; ++tj) {
            short8 bf = *(const short8*)&g_wbf[(tj * 16 + l16) * (2 * ND) + ko];
            acc2[tj] = __builtin_amdgcn_mfma_f32_16x16x32_bf16(a, bf, acc2[tj], 0, 0, 0);
        }
    }

    float bvals[4];
    #pragma unroll
    for (int tj = 0; tj < 4; ++tj) bvals[tj] = bias[tj * 16 + l16];

    float* ob = out + ((size_t)b * NP + half * 64) * ND;
    #pragma unroll
    for (int tj = 0; tj < 4; ++tj)
        #pragma unroll
        for (int r = 0; r < 4; ++r) {
            int row = R0L + quad * 4 + r;
            ob[(size_t)row * ND + tj * 16 + l16] = fast_tanh(acc2[tj][r] + bvals[tj]);
        }
}

extern "C" void kernel_launch(void* const* d_in, const int* in_sizes, int n_in,
                              void* d_out, int out_size, void* d_ws, size_t ws_size,
                              hipStream_t stream) {
    const float* hidden = (const float*)d_in[0];
    const float* dist   = (const float*)d_in[1];
    const float* bear   = (const float*)d_in[2];
    const float* head   = (const float*)d_in[3];
    const float* smask  = (const float*)d_in[4];
    const float* domain = (const float*)d_in[5];
    const float* W      = (const float*)d_in[6];
    const float* bias   = (const float*)d_in[7];
    float* out = (float*)d_out;
    short* wbuf = (short*)d_ws;         // 16.8 MB bf16 E (ws is 268 MB)

    prep_w<<<dim3(8), dim3(256), 0, stream>>>(W);
    exp_kernel<<<dim3(NB * 8), dim3(256), 0, stream>>>(
        dist, bear, head, smask, domain, wbuf);
    fuse_kernel<<<dim3(NB * 2), dim3(256), 0, stream>>>(
        wbuf, hidden, bias, out);
}